// Round 16
// baseline (604.391 us; speedup 1.0000x reference)
//
#include <hip/hip_runtime.h>
#include <cstdint>
#include <cstddef>

#define D_DIM 2048
#define D_HID 8192
#define N_TOK 8192

typedef int v4i __attribute__((ext_vector_type(4)));
typedef int v16i __attribute__((ext_vector_type(16)));
typedef float v4f __attribute__((ext_vector_type(4)));
typedef _Float16 v8h __attribute__((ext_vector_type(8)));

__device__ __forceinline__ void gload16(const void* g, void* l) {
  __builtin_amdgcn_global_load_lds(
      (__attribute__((address_space(1))) void*)(void*)(const_cast<void*>(g)),
      (__attribute__((address_space(3))) void*)(void*)(l), 16, 0, 0);
}

__device__ __forceinline__ unsigned pack4i8(int a, int b, int c, int d) {
  return (unsigned)(a & 255) | ((unsigned)(b & 255) << 8) |
         ((unsigned)(c & 255) << 16) | ((unsigned)(d & 255) << 24);
}

__device__ __forceinline__ int clampi(int v, int lo, int hi) {
  return v < lo ? lo : (v > hi ? hi : v);
}

// Branch-free exact-GELU via Abramowitz-Stegun 7.1.26 erf (|eps| <= 1.5e-7 abs).
__device__ __forceinline__ float gelu_fast(float c) {
  const float ax = fabsf(c) * 0.70710678118654752440f;
  const float t = 1.0f / fmaf(0.3275911f, ax, 1.0f);
  const float poly =
      t * fmaf(t, fmaf(t, fmaf(t, fmaf(t, 1.061405429f, -1.453152027f),
                               1.421413741f), -0.284496736f), 0.254829592f);
  const float e = 1.0f - poly * __expf(-ax * ax);
  const float es = copysignf(e, c);
  return 0.5f * c * (1.0f + es);
}

// ---------------- weight |w| sum (fixed-order f64, deterministic) ------------
__global__ __launch_bounds__(256) void wsum_k(const float* __restrict__ w1,
                                              const float* __restrict__ w2,
                                              double* __restrict__ part) {
  const int b = blockIdx.x;
  const float* w = (b < 1024) ? w1 : w2;
  const size_t base = (size_t)(b & 1023) * 16384;
  const int t = threadIdx.x;
  double s = 0.0;
  for (int i = 0; i < 64; ++i) s += fabs((double)w[base + (size_t)i * 256 + t]);
  __shared__ double red[256];
  red[t] = s;
  __syncthreads();
  for (int st = 128; st; st >>= 1) {
    if (t < st) red[t] += red[t + st];
    __syncthreads();
  }
  if (!t) part[b] = red[0];
}

__global__ __launch_bounds__(256) void wfinal_k(const double* __restrict__ part,
                                                double* __restrict__ swd,
                                                float* __restrict__ wsc) {
  __shared__ double red[256];
  const int t = threadIdx.x;
  for (int m = 0; m < 2; ++m) {
    double s = part[m * 1024 + t] + part[m * 1024 + 256 + t] +
               part[m * 1024 + 512 + t] + part[m * 1024 + 768 + t];
    red[t] = s;
    __syncthreads();
    for (int st = 128; st; st >>= 1) {
      if (t < st) red[t] += red[t + st];
      __syncthreads();
    }
    if (!t) {
      double mean = red[0] / 16777216.0;
      double m2 = fmax(mean, 1e-5);
      swd[m] = 1.0 / m2;
      wsc[m] = (float)m2;
    }
    __syncthreads();
  }
}

// ---------------- ternary weight quant (f64 decision, half-even) -------------
__global__ __launch_bounds__(256) void wquant_k(const float* __restrict__ w,
                                                int8_t* __restrict__ q,
                                                const double* __restrict__ swd, int idx) {
  const double s = swd[idx];
  const size_t i = ((size_t)blockIdx.x * 256 + threadIdx.x) * 4;
  const float4 v = *(const float4*)&w[i];
  const int q0 = clampi((int)__builtin_rint((double)v.x * s), -1, 1);
  const int q1 = clampi((int)__builtin_rint((double)v.y * s), -1, 1);
  const int q2 = clampi((int)__builtin_rint((double)v.z * s), -1, 1);
  const int q3 = clampi((int)__builtin_rint((double)v.w * s), -1, 1);
  *(unsigned*)&q[i] = pack4i8(q0, q1, q2, q3);
}

// ---------------- fused RMSNorm + per-token absmax int8 quant ----------------
__global__ __launch_bounds__(256) void rmsq_k(const float* __restrict__ x,
                                              const float* __restrict__ gamma,
                                              int8_t* __restrict__ qx,
                                              float* __restrict__ sxinv) {
  const int row = blockIdx.x, t = threadIdx.x;
  const float* xr = x + (size_t)row * D_DIM;
  const v4f v0 = __builtin_nontemporal_load((const v4f*)&xr[t * 4]);
  const v4f v1 = __builtin_nontemporal_load((const v4f*)&xr[1024 + t * 4]);
  double xs[8] = {v0[0], v0[1], v0[2], v0[3], v1[0], v1[1], v1[2], v1[3]};
  double ssq = 0.0;
#pragma unroll
  for (int j = 0; j < 8; ++j) ssq += xs[j] * xs[j];
  __shared__ double red[256];
  red[t] = ssq;
  __syncthreads();
  for (int st = 128; st; st >>= 1) {
    if (t < st) red[t] += red[t + st];
    __syncthreads();
  }
  const double rn = 1.0 / sqrt(red[0] / (double)D_DIM + 1e-6);
  __syncthreads();
  const float4 g0 = *(const float4*)&gamma[t * 4];
  const float4 g1 = *(const float4*)&gamma[1024 + t * 4];
  const double gs[8] = {g0.x, g0.y, g0.z, g0.w, g1.x, g1.y, g1.z, g1.w};
  double xn[8], am = 0.0;
#pragma unroll
  for (int j = 0; j < 8; ++j) {
    xn[j] = xs[j] * rn * gs[j];
    am = fmax(am, fabs(xn[j]));
  }
  red[t] = am;
  __syncthreads();
  for (int st = 128; st; st >>= 1) {
    if (t < st) red[t] = fmax(red[t], red[t + st]);
    __syncthreads();
  }
  const double amax = fmax(red[0], 1e-5);
  const double s = 127.0 / amax;
  int q[8];
#pragma unroll
  for (int j = 0; j < 8; ++j) q[j] = clampi((int)__builtin_rint(xn[j] * s), -128, 127);
  unsigned* qo = (unsigned*)(qx + (size_t)row * D_DIM);
  qo[t] = pack4i8(q[0], q[1], q[2], q[3]);
  qo[256 + t] = pack4i8(q[4], q[5], q[6], q[7]);
  if (!t) sxinv[row] = (float)(amax / 127.0);
}

// ---------------- per-token quant of f16 gelu(h) (path A16) ------------------
__global__ __launch_bounds__(256) void hquant16_k(const _Float16* __restrict__ g16,
                                                  int8_t* __restrict__ qh,
                                                  const unsigned* __restrict__ amaxh,
                                                  float* __restrict__ shinv) {
  const int row = blockIdx.x, t = threadIdx.x;
  const _Float16* gr = g16 + (size_t)row * D_HID;
  const double am = fmax((double)__uint_as_float(amaxh[row]), 1e-5);
  const double s = 127.0 / am;
  if (!t) shinv[row] = (float)(am / 127.0);
  unsigned* qo = (unsigned*)(qh + (size_t)row * D_HID);
#pragma unroll
  for (int j = 0; j < 4; ++j) {
    const v8h v = *(const v8h*)&gr[j * 2048 + t * 8];
    int q[8];
#pragma unroll
    for (int e = 0; e < 8; ++e)
      q[e] = clampi((int)__builtin_rint((double)(float)v[e] * s), -128, 127);
    qo[j * 512 + t * 2 + 0] = pack4i8(q[0], q[1], q[2], q[3]);
    qo[j * 512 + t * 2 + 1] = pack4i8(q[4], q[5], q[6], q[7]);
  }
}

__global__ __launch_bounds__(256) void scalefix_k(const unsigned* __restrict__ amaxh,
                                                  float* __restrict__ shinv) {
  const int i = blockIdx.x * 256 + threadIdx.x;
  if (i < N_TOK)
    shinv[i] = (float)(fmax((double)__uint_as_float(amaxh[i]), 1e-5) / 127.0);
}

// == int8 NT GEMM, 128x128, BK=64, dbuf, 4 blocks/CU, 32x32x32 MFMA shape =====
// R15 structure (occupancy 41%, conflicts 0, FETCH ~95 MB, supercolumn L2)
// with the MFMA shape swapped 16x16x64 -> 32x32x32: per tile 8 MFMA (was 16,
// issue slots halve; ceiling 3944->4404 TOPS), same 8 ds_read_b128, same LDS
// bytes, C-stores 2x better coalesced (32 contiguous cols/half-wave).
// A/B fragment: row(col)=lane&31, kchunk=lane>>5 (16B); C/D: col=lane&31,
// row=(reg&3)+8(reg>>2)+4(lane>>5) [HW-verified m74/m101].
// LDS subblock [32 rows][4 chunks], chunk perm cpos = c ^ (row&3):
// fragment reads = 2 lanes/bank (free); staging source keeps 4rows-x-64B
// coalescing; involution identical on both sides (rule 21).
// EPI: 0 gelu rowmax; 1 gelu + f32 nt-store + rowmax; 2 dequant nt-store;
//      3 gelu + i8 quant store; 4 gelu + f16 cached store + rowmax (A16).
template <int EPI>
__global__ __launch_bounds__(256, 4) void gemm4_i8_k(const int8_t* __restrict__ A,
                                                     const int8_t* __restrict__ B, int K,
                                                     int NB_X,
                                                     float* __restrict__ Cf,
                                                     _Float16* __restrict__ Ch,
                                                     int8_t* __restrict__ Cq, int ldc,
                                                     const float* __restrict__ rowf,
                                                     const float* __restrict__ wscp,
                                                     unsigned* __restrict__ amax) {
  __shared__ __align__(16) int8_t Al[2][8192];
  __shared__ __align__(16) int8_t Bl[2][8192];
  const int tid = threadIdx.x;
  const int wave = tid >> 6, lane = tid & 63;
  const int wr = wave >> 1, wc = wave & 1;  // 2x2 waves, 64x64 each

  const int nwg = gridDim.x;  // multiple of 8; super-columns of 8 col-panels
  const int bid = blockIdx.x;
  const int lid = (bid & 7) * (nwg >> 3) + (bid >> 3);  // XCD-contiguous
  const int grp = lid >> 9;
  const int rem = lid & 511;
  const int by = rem >> 3;
  const int bx = (grp << 3) | (rem & 7);
  const int row0 = by * 128, col0 = bx * 128;

  // staging source (per wave stages its 32-row subblock, 2 instr halves):
  // slot=lane -> row (lane>>2), chunk (lane&3)^((lane>>2)&3)
  const int srow = lane >> 2;
  const int skb = ((lane & 3) ^ ((lane >> 2) & 3)) * 16;
  const size_t aG0 = (size_t)(row0 + wave * 32 + srow) * K + skb;
  const size_t aG1 = aG0 + (size_t)16 * K;
  const size_t bG0 = (size_t)(col0 + wave * 32 + srow) * K + skb;
  const size_t bG1 = bG0 + (size_t)16 * K;
  const int ls0 = wave * 2048, ls1 = wave * 2048 + 1024;
  const int NT = K >> 6;

  v16i acc[2][2];
#pragma unroll
  for (int mi = 0; mi < 2; ++mi)
#pragma unroll
    for (int ni = 0; ni < 2; ++ni)
#pragma unroll
      for (int e = 0; e < 16; ++e) acc[mi][ni][e] = 0;

  // fragment read offsets: row=lane&31, chunk c = s*2 + (lane>>5), perm'd
  const int arow = lane & 31;
  const int kc = lane >> 5;
  const int fo0 = arow * 64 + (((0 + kc) ^ (arow & 3)) * 16);  // kstep 0
  const int fo1 = arow * 64 + (((2 + kc) ^ (arow & 3)) * 16);  // kstep 1
  const int asb = wr * 2 * 2048;  // A subblocks wr*2, wr*2+1
  const int bsb = wc * 2 * 2048;

#define STG(buf, T)                                                            \
  do {                                                                         \
    const size_t ko_ = (size_t)(T) * 64;                                       \
    gload16(A + aG0 + ko_, &Al[buf][ls0]);                                     \
    gload16(A + aG1 + ko_, &Al[buf][ls1]);                                     \
    gload16(B + bG0 + ko_, &Bl[buf][ls0]);                                     \
    gload16(B + bG1 + ko_, &Bl[buf][ls1]);                                     \
  } while (0)

  // prologue
  STG(0, 0);
  asm volatile("s_waitcnt vmcnt(0)" ::: "memory");
  __syncthreads();

  int buf = 0;
#pragma unroll 1
  for (int t = 0; t < NT; ++t) {
    if (t + 1 < NT) STG(buf ^ 1, t + 1);  // issue-early
    v4i a00 = *(const v4i*)&Al[buf][asb + 0 * 2048 + fo0];
    v4i a10 = *(const v4i*)&Al[buf][asb + 1 * 2048 + fo0];
    v4i b00 = *(const v4i*)&Bl[buf][bsb + 0 * 2048 + fo0];
    v4i b10 = *(const v4i*)&Bl[buf][bsb + 1 * 2048 + fo0];
    v4i a01 = *(const v4i*)&Al[buf][asb + 0 * 2048 + fo1];
    v4i a11 = *(const v4i*)&Al[buf][asb + 1 * 2048 + fo1];
    v4i b01 = *(const v4i*)&Bl[buf][bsb + 0 * 2048 + fo1];
    v4i b11 = *(const v4i*)&Bl[buf][bsb + 1 * 2048 + fo1];
    __builtin_amdgcn_s_setprio(1);
    acc[0][0] = __builtin_amdgcn_mfma_i32_32x32x32_i8(a00, b00, acc[0][0], 0, 0, 0);
    acc[0][1] = __builtin_amdgcn_mfma_i32_32x32x32_i8(a00, b10, acc[0][1], 0, 0, 0);
    acc[1][0] = __builtin_amdgcn_mfma_i32_32x32x32_i8(a10, b00, acc[1][0], 0, 0, 0);
    acc[1][1] = __builtin_amdgcn_mfma_i32_32x32x32_i8(a10, b10, acc[1][1], 0, 0, 0);
    acc[0][0] = __builtin_amdgcn_mfma_i32_32x32x32_i8(a01, b01, acc[0][0], 0, 0, 0);
    acc[0][1] = __builtin_amdgcn_mfma_i32_32x32x32_i8(a01, b11, acc[0][1], 0, 0, 0);
    acc[1][0] = __builtin_amdgcn_mfma_i32_32x32x32_i8(a11, b01, acc[1][0], 0, 0, 0);
    acc[1][1] = __builtin_amdgcn_mfma_i32_32x32x32_i8(a11, b11, acc[1][1], 0, 0, 0);
    __builtin_amdgcn_s_setprio(0);
    asm volatile("s_waitcnt vmcnt(0)" ::: "memory");  // wait-late (absorbed)
    __syncthreads();
    buf ^= 1;
  }
#undef STG

  // ---- epilogue (C/D: col=lane&31, row=(r&3)+8*(r>>2)+4*(lane>>5)) ----
  const float mw = wscp[0];
  const int ccol = lane & 31;
  const int rbase = (lane >> 5) * 4;
#pragma unroll
  for (int mi = 0; mi < 2; ++mi) {
#pragma unroll
    for (int r = 0; r < 16; ++r) {
      const int grow = row0 + wr * 64 + mi * 32 + (r & 3) + 8 * (r >> 2) + rbase;
      const float f = rowf[grow] * mw;
      if constexpr (EPI == 0 || EPI == 1 || EPI == 4) {
        float rmax = 0.f;
#pragma unroll
        for (int ni = 0; ni < 2; ++ni) {
          const int gcol = col0 + wc * 64 + ni * 32 + ccol;
          const float c = (float)acc[mi][ni][r] * f;
          const float gv = gelu_fast(c);
          if constexpr (EPI == 1)
            __builtin_nontemporal_store(gv, &Cf[(size_t)grow * ldc + gcol]);
          if constexpr (EPI == 4)
            Ch[(size_t)grow * ldc + gcol] = (_Float16)gv;
          rmax = fmaxf(rmax, fabsf(gv));
        }
#pragma unroll
        for (int sh = 1; sh < 32; sh <<= 1) rmax = fmaxf(rmax, __shfl_xor(rmax, sh));
        if (ccol == 0) atomicMax(&amax[grow], __float_as_uint(rmax));
      } else if constexpr (EPI == 3) {
        const double s = 127.0 / fmax((double)__uint_as_float(amax[grow]), 1e-5);
#pragma unroll
        for (int ni = 0; ni < 2; ++ni) {
          const int gcol = col0 + wc * 64 + ni * 32 + ccol;
          const float c = (float)acc[mi][ni][r] * f;
          const float gv = gelu_fast(c);
          Cq[(size_t)grow * ldc + gcol] =
              (int8_t)clampi((int)__builtin_rint((double)gv * s), -128, 127);
        }
      } else {
#pragma unroll
        for (int ni = 0; ni < 2; ++ni) {
          const int gcol = col0 + wc * 64 + ni * 32 + ccol;
          __builtin_nontemporal_store((float)acc[mi][ni][r] * f,
                                      &Cf[(size_t)grow * ldc + gcol]);
        }
      }
    }
  }
}

__global__ void fill_k(float* p, int n, float v) {
  int i = blockIdx.x * 256 + threadIdx.x;
  if (i < n) p[i] = v;
}

extern "C" void kernel_launch(void* const* d_in, const int* in_sizes, int n_in, void* d_out,
                              int out_size, void* d_ws, size_t ws_size, hipStream_t stream) {
  const float* x = (const float*)d_in[0];
  const float* w1 = (const float*)d_in[1];
  const float* w2 = (const float*)d_in[2];
  const float* gamma = (const float*)d_in[3];
  float* out = (float*)d_out;
  char* ws = (char*)d_ws;

  const size_t SQX = (size_t)N_TOK * D_DIM;
  const size_t SQW1 = (size_t)D_HID * D_DIM;
  const size_t SQW2 = (size_t)D_DIM * D_HID;
  const size_t SQH = (size_t)N_TOK * D_HID;
  const size_t SG16 = (size_t)N_TOK * D_HID * 2;  // 128 MiB f16 g

  size_t off = 0;
  int8_t* qx = (int8_t*)(ws + off);  off += SQX;
  int8_t* qw1 = (int8_t*)(ws + off); off += SQW1;
  int8_t* qw2 = (int8_t*)(ws + off); off += SQW2;
  int8_t* qh = (int8_t*)(ws + off);  off += SQH;
  float* sxinv = (float*)(ws + off);       off += (size_t)N_TOK * 4;
  unsigned* amaxh = (unsigned*)(ws + off); off += (size_t)N_TOK * 4;
  float* shinv = (float*)(ws + off);       off += (size_t)N_TOK * 4;
  double* wpart = (double*)(ws + off);     off += 2048 * 8;
  double* swd = (double*)(ws + off);       off += 2 * 8;
  float* wsc = (float*)(ws + off);         off += 2 * 4;
  off = (off + 255) & ~(size_t)255;
  const size_t needB = off;
  _Float16* g16 = (_Float16*)(ws + off);
  const size_t needA16 = off + SG16;

  if (ws_size < needB) {
    const float v = 100000.0f + (float)(ws_size >> 20);
    fill_k<<<(out_size + 255) / 256, 256, 0, stream>>>(out, out_size, v);
    return;
  }
  const bool pathA16 = (ws_size >= needA16);

  hipMemsetAsync(amaxh, 0, (size_t)N_TOK * 4, stream);
  wsum_k<<<2048, 256, 0, stream>>>(w1, w2, wpart);
  wfinal_k<<<1, 256, 0, stream>>>(wpart, swd, wsc);
  wquant_k<<<16384, 256, 0, stream>>>(w1, qw1, swd, 0);
  wquant_k<<<16384, 256, 0, stream>>>(w2, qw2, swd, 1);
  rmsq_k<<<N_TOK, 256, 0, stream>>>(x, gamma, qx, sxinv);

  const int nwg1 = (N_TOK / 128) * (D_HID / 128);  // 4096
  const int nwg2 = (N_TOK / 128) * (D_DIM / 128);  // 1024
  if (pathA16) {
    gemm4_i8_k<4><<<nwg1, 256, 0, stream>>>(qx, qw1, D_DIM, D_HID / 128, nullptr, g16,
                                            nullptr, D_HID, sxinv, wsc + 0, amaxh);
    hquant16_k<<<N_TOK, 256, 0, stream>>>(g16, qh, amaxh, shinv);
  } else {
    gemm4_i8_k<0><<<nwg1, 256, 0, stream>>>(qx, qw1, D_DIM, D_HID / 128, nullptr, nullptr,
                                            nullptr, D_HID, sxinv, wsc + 0, amaxh);
    scalefix_k<<<(N_TOK + 255) / 256, 256, 0, stream>>>(amaxh, shinv);
    gemm4_i8_k<3><<<nwg1, 256, 0, stream>>>(qx, qw1, D_DIM, D_HID / 128, nullptr, nullptr,
                                            qh, D_HID, sxinv, wsc + 0, amaxh);
  }
  gemm4_i8_k<2><<<nwg2, 256, 0, stream>>>(qh, qw2, D_HID, D_DIM / 128, out, nullptr,
                                          nullptr, D_DIM, shinv, wsc + 1, nullptr);
}

// Round 17
// 586.508 us; speedup vs baseline: 1.0305x; 1.0305x over previous
//
#include <hip/hip_runtime.h>
#include <cstdint>
#include <cstddef>

#define D_DIM 2048
#define D_HID 8192
#define N_TOK 8192

typedef int v4i __attribute__((ext_vector_type(4)));
typedef int v16i __attribute__((ext_vector_type(16)));
typedef float v4f __attribute__((ext_vector_type(4)));
typedef _Float16 v8h __attribute__((ext_vector_type(8)));

__device__ __forceinline__ void gload16(const void* g, void* l) {
  __builtin_amdgcn_global_load_lds(
      (__attribute__((address_space(1))) void*)(void*)(const_cast<void*>(g)),
      (__attribute__((address_space(3))) void*)(void*)(l), 16, 0, 0);
}

__device__ __forceinline__ unsigned pack4i8(int a, int b, int c, int d) {
  return (unsigned)(a & 255) | ((unsigned)(b & 255) << 8) |
         ((unsigned)(c & 255) << 16) | ((unsigned)(d & 255) << 24);
}

__device__ __forceinline__ int clampi(int v, int lo, int hi) {
  return v < lo ? lo : (v > hi ? hi : v);
}

// Branch-free exact-GELU via Abramowitz-Stegun 7.1.26 erf (|eps| <= 1.5e-7 abs).
__device__ __forceinline__ float gelu_fast(float c) {
  const float ax = fabsf(c) * 0.70710678118654752440f;
  const float t = 1.0f / fmaf(0.3275911f, ax, 1.0f);
  const float poly =
      t * fmaf(t, fmaf(t, fmaf(t, fmaf(t, 1.061405429f, -1.453152027f),
                               1.421413741f), -0.284496736f), 0.254829592f);
  const float e = 1.0f - poly * __expf(-ax * ax);
  const float es = copysignf(e, c);
  return 0.5f * c * (1.0f + es);
}

// ---------------- weight |w| sum (fixed-order f64, deterministic) ------------
__global__ __launch_bounds__(256) void wsum_k(const float* __restrict__ w1,
                                              const float* __restrict__ w2,
                                              double* __restrict__ part) {
  const int b = blockIdx.x;
  const float* w = (b < 1024) ? w1 : w2;
  const size_t base = (size_t)(b & 1023) * 16384;
  const int t = threadIdx.x;
  double s = 0.0;
  for (int i = 0; i < 64; ++i) s += fabs((double)w[base + (size_t)i * 256 + t]);
  __shared__ double red[256];
  red[t] = s;
  __syncthreads();
  for (int st = 128; st; st >>= 1) {
    if (t < st) red[t] += red[t + st];
    __syncthreads();
  }
  if (!t) part[b] = red[0];
}

__global__ __launch_bounds__(256) void wfinal_k(const double* __restrict__ part,
                                                double* __restrict__ swd,
                                                float* __restrict__ wsc) {
  __shared__ double red[256];
  const int t = threadIdx.x;
  for (int m = 0; m < 2; ++m) {
    double s = part[m * 1024 + t] + part[m * 1024 + 256 + t] +
               part[m * 1024 + 512 + t] + part[m * 1024 + 768 + t];
    red[t] = s;
    __syncthreads();
    for (int st = 128; st; st >>= 1) {
      if (t < st) red[t] += red[t + st];
      __syncthreads();
    }
    if (!t) {
      double mean = red[0] / 16777216.0;
      double m2 = fmax(mean, 1e-5);
      swd[m] = 1.0 / m2;
      wsc[m] = (float)m2;
    }
    __syncthreads();
  }
}

// ---------------- ternary weight quant (f64 decision, half-even) -------------
__global__ __launch_bounds__(256) void wquant_k(const float* __restrict__ w,
                                                int8_t* __restrict__ q,
                                                const double* __restrict__ swd, int idx) {
  const double s = swd[idx];
  const size_t i = ((size_t)blockIdx.x * 256 + threadIdx.x) * 4;
  const float4 v = *(const float4*)&w[i];
  const int q0 = clampi((int)__builtin_rint((double)v.x * s), -1, 1);
  const int q1 = clampi((int)__builtin_rint((double)v.y * s), -1, 1);
  const int q2 = clampi((int)__builtin_rint((double)v.z * s), -1, 1);
  const int q3 = clampi((int)__builtin_rint((double)v.w * s), -1, 1);
  *(unsigned*)&q[i] = pack4i8(q0, q1, q2, q3);
}

// ---------------- fused RMSNorm + per-token absmax int8 quant ----------------
__global__ __launch_bounds__(256) void rmsq_k(const float* __restrict__ x,
                                              const float* __restrict__ gamma,
                                              int8_t* __restrict__ qx,
                                              float* __restrict__ sxinv) {
  const int row = blockIdx.x, t = threadIdx.x;
  const float* xr = x + (size_t)row * D_DIM;
  const v4f v0 = __builtin_nontemporal_load((const v4f*)&xr[t * 4]);
  const v4f v1 = __builtin_nontemporal_load((const v4f*)&xr[1024 + t * 4]);
  double xs[8] = {v0[0], v0[1], v0[2], v0[3], v1[0], v1[1], v1[2], v1[3]};
  double ssq = 0.0;
#pragma unroll
  for (int j = 0; j < 8; ++j) ssq += xs[j] * xs[j];
  __shared__ double red[256];
  red[t] = ssq;
  __syncthreads();
  for (int st = 128; st; st >>= 1) {
    if (t < st) red[t] += red[t + st];
    __syncthreads();
  }
  const double rn = 1.0 / sqrt(red[0] / (double)D_DIM + 1e-6);
  __syncthreads();
  const float4 g0 = *(const float4*)&gamma[t * 4];
  const float4 g1 = *(const float4*)&gamma[1024 + t * 4];
  const double gs[8] = {g0.x, g0.y, g0.z, g0.w, g1.x, g1.y, g1.z, g1.w};
  double xn[8], am = 0.0;
#pragma unroll
  for (int j = 0; j < 8; ++j) {
    xn[j] = xs[j] * rn * gs[j];
    am = fmax(am, fabs(xn[j]));
  }
  red[t] = am;
  __syncthreads();
  for (int st = 128; st; st >>= 1) {
    if (t < st) red[t] = fmax(red[t], red[t + st]);
    __syncthreads();
  }
  const double amax = fmax(red[0], 1e-5);
  const double s = 127.0 / amax;
  int q[8];
#pragma unroll
  for (int j = 0; j < 8; ++j) q[j] = clampi((int)__builtin_rint(xn[j] * s), -128, 127);
  unsigned* qo = (unsigned*)(qx + (size_t)row * D_DIM);
  qo[t] = pack4i8(q[0], q[1], q[2], q[3]);
  qo[256 + t] = pack4i8(q[4], q[5], q[6], q[7]);
  if (!t) sxinv[row] = (float)(amax / 127.0);
}

// ---------------- per-token quant of f16 gelu(h) (path A16) ------------------
__global__ __launch_bounds__(256) void hquant16_k(const _Float16* __restrict__ g16,
                                                  int8_t* __restrict__ qh,
                                                  const unsigned* __restrict__ amaxh,
                                                  float* __restrict__ shinv) {
  const int row = blockIdx.x, t = threadIdx.x;
  const _Float16* gr = g16 + (size_t)row * D_HID;
  const double am = fmax((double)__uint_as_float(amaxh[row]), 1e-5);
  const double s = 127.0 / am;
  if (!t) shinv[row] = (float)(am / 127.0);
  unsigned* qo = (unsigned*)(qh + (size_t)row * D_HID);
#pragma unroll
  for (int j = 0; j < 4; ++j) {
    const v8h v = __builtin_nontemporal_load((const v8h*)&gr[j * 2048 + t * 8]);
    int q[8];
#pragma unroll
    for (int e = 0; e < 8; ++e)
      q[e] = clampi((int)__builtin_rint((double)(float)v[e] * s), -128, 127);
    qo[j * 512 + t * 2 + 0] = pack4i8(q[0], q[1], q[2], q[3]);
    qo[j * 512 + t * 2 + 1] = pack4i8(q[4], q[5], q[6], q[7]);
  }
}

__global__ __launch_bounds__(256) void scalefix_k(const unsigned* __restrict__ amaxh,
                                                  float* __restrict__ shinv) {
  const int i = blockIdx.x * 256 + threadIdx.x;
  if (i < N_TOK)
    shinv[i] = (float)(fmax((double)__uint_as_float(amaxh[i]), 1e-5) / 127.0);
}

// == int8 NT GEMM, 128x128, BK=64, dbuf, 4 blocks/CU, 32x32x32, kstep-slots ===
// R16 post-mortem: 32x32 fragment at row-major [32][64B] is irreducibly >=4-way
// bank-conflicted (row stride 64B -> only 8 bank-start positions). Fix: store
// each K=32 step's 1024B as [slot][16B] with slot = row*2 + kc. Fragment read
// slot = (lane&31)*2 + (lane>>5) is a bijection onto 64 CONTIGUOUS slots ->
// sequential bank sweep, zero conflicts (same property as the verified 16x16
// layout). Staging: gload slot=lane <-> row (lane>>1), half (lane&1): lane
// pairs read 32B contiguous per row (granularity 64->32B; VMEM is 15% HBM,
// instruction count unchanged at 16 gloads/tile). MFMA fragment + C/D layouts
// are IDENTICAL to R16, already validated end-to-end (absmax bit-identical).
// EPI: 0 gelu rowmax; 1 gelu + f32 nt-store + rowmax; 2 dequant nt-store;
//      3 gelu + i8 quant store; 4 gelu + f16 nt-store + rowmax (path A16).
template <int EPI>
__global__ __launch_bounds__(256, 4) void gemm4_i8_k(const int8_t* __restrict__ A,
                                                     const int8_t* __restrict__ B, int K,
                                                     int NB_X,
                                                     float* __restrict__ Cf,
                                                     _Float16* __restrict__ Ch,
                                                     int8_t* __restrict__ Cq, int ldc,
                                                     const float* __restrict__ rowf,
                                                     const float* __restrict__ wscp,
                                                     unsigned* __restrict__ amax) {
  __shared__ __align__(16) int8_t Al[2][8192];
  __shared__ __align__(16) int8_t Bl[2][8192];
  const int tid = threadIdx.x;
  const int wave = tid >> 6, lane = tid & 63;
  const int wr = wave >> 1, wc = wave & 1;  // 2x2 waves, 64x64 each

  const int nwg = gridDim.x;  // multiple of 8; super-columns of 8 col-panels
  const int bid = blockIdx.x;
  const int lid = (bid & 7) * (nwg >> 3) + (bid >> 3);  // XCD-contiguous
  const int grp = lid >> 9;
  const int rem = lid & 511;
  const int by = rem >> 3;
  const int bx = (grp << 3) | (rem & 7);
  const int row0 = by * 128, col0 = bx * 128;

  // staging source: slot=lane -> row (lane>>1), 16B-half (lane&1)
  const int srow = lane >> 1;
  const int shalf = (lane & 1) * 16;
  const size_t aGs = (size_t)(row0 + wave * 32 + srow) * K + shalf;
  const size_t bGs = (size_t)(col0 + wave * 32 + srow) * K + shalf;
  const int lsb = wave * 2048;  // wave's subblock base (A sub wave, B sub wave)
  const int NT = K >> 6;

  v16i acc[2][2];
#pragma unroll
  for (int mi = 0; mi < 2; ++mi)
#pragma unroll
    for (int ni = 0; ni < 2; ++ni)
#pragma unroll
      for (int e = 0; e < 16; ++e) acc[mi][ni][e] = 0;

  // fragment read: slot = (lane&31)*2 + (lane>>5), contiguous 16B slots
  const int fo = (((lane & 31) * 2 + (lane >> 5)) * 16);
  const int asb = wr * 2 * 2048;  // A subblocks wr*2, wr*2+1
  const int bsb = wc * 2 * 2048;

#define STG(buf, T)                                                            \
  do {                                                                         \
    const size_t ko_ = (size_t)(T) * 64;                                       \
    gload16(A + aGs + ko_, &Al[buf][lsb]);                                     \
    gload16(A + aGs + ko_ + 32, &Al[buf][lsb + 1024]);                         \
    gload16(B + bGs + ko_, &Bl[buf][lsb]);                                     \
    gload16(B + bGs + ko_ + 32, &Bl[buf][lsb + 1024]);                         \
  } while (0)

  // prologue
  STG(0, 0);
  asm volatile("s_waitcnt vmcnt(0)" ::: "memory");
  __syncthreads();

  int buf = 0;
#pragma unroll 1
  for (int t = 0; t < NT; ++t) {
    if (t + 1 < NT) STG(buf ^ 1, t + 1);  // issue-early
    v4i a00 = *(const v4i*)&Al[buf][asb + 0 * 2048 + 0 * 1024 + fo];
    v4i a10 = *(const v4i*)&Al[buf][asb + 1 * 2048 + 0 * 1024 + fo];
    v4i b00 = *(const v4i*)&Bl[buf][bsb + 0 * 2048 + 0 * 1024 + fo];
    v4i b10 = *(const v4i*)&Bl[buf][bsb + 1 * 2048 + 0 * 1024 + fo];
    v4i a01 = *(const v4i*)&Al[buf][asb + 0 * 2048 + 1 * 1024 + fo];
    v4i a11 = *(const v4i*)&Al[buf][asb + 1 * 2048 + 1 * 1024 + fo];
    v4i b01 = *(const v4i*)&Bl[buf][bsb + 0 * 2048 + 1 * 1024 + fo];
    v4i b11 = *(const v4i*)&Bl[buf][bsb + 1 * 2048 + 1 * 1024 + fo];
    __builtin_amdgcn_s_setprio(1);
    acc[0][0] = __builtin_amdgcn_mfma_i32_32x32x32_i8(a00, b00, acc[0][0], 0, 0, 0);
    acc[0][1] = __builtin_amdgcn_mfma_i32_32x32x32_i8(a00, b10, acc[0][1], 0, 0, 0);
    acc[1][0] = __builtin_amdgcn_mfma_i32_32x32x32_i8(a10, b00, acc[1][0], 0, 0, 0);
    acc[1][1] = __builtin_amdgcn_mfma_i32_32x32x32_i8(a10, b10, acc[1][1], 0, 0, 0);
    acc[0][0] = __builtin_amdgcn_mfma_i32_32x32x32_i8(a01, b01, acc[0][0], 0, 0, 0);
    acc[0][1] = __builtin_amdgcn_mfma_i32_32x32x32_i8(a01, b11, acc[0][1], 0, 0, 0);
    acc[1][0] = __builtin_amdgcn_mfma_i32_32x32x32_i8(a11, b01, acc[1][0], 0, 0, 0);
    acc[1][1] = __builtin_amdgcn_mfma_i32_32x32x32_i8(a11, b11, acc[1][1], 0, 0, 0);
    __builtin_amdgcn_s_setprio(0);
    asm volatile("s_waitcnt vmcnt(0)" ::: "memory");  // wait-late (absorbed)
    __syncthreads();
    buf ^= 1;
  }
#undef STG

  // ---- epilogue (C/D: col=lane&31, row=(r&3)+8*(r>>2)+4*(lane>>5)) ----
  const float mw = wscp[0];
  const int ccol = lane & 31;
  const int rbase = (lane >> 5) * 4;
#pragma unroll
  for (int mi = 0; mi < 2; ++mi) {
#pragma unroll
    for (int r = 0; r < 16; ++r) {
      const int grow = row0 + wr * 64 + mi * 32 + (r & 3) + 8 * (r >> 2) + rbase;
      const float f = rowf[grow] * mw;
      if constexpr (EPI == 0 || EPI == 1 || EPI == 4) {
        float rmax = 0.f;
#pragma unroll
        for (int ni = 0; ni < 2; ++ni) {
          const int gcol = col0 + wc * 64 + ni * 32 + ccol;
          const float c = (float)acc[mi][ni][r] * f;
          const float gv = gelu_fast(c);
          if constexpr (EPI == 1)
            __builtin_nontemporal_store(gv, &Cf[(size_t)grow * ldc + gcol]);
          if constexpr (EPI == 4)
            __builtin_nontemporal_store((_Float16)gv, &Ch[(size_t)grow * ldc + gcol]);
          rmax = fmaxf(rmax, fabsf(gv));
        }
#pragma unroll
        for (int sh = 1; sh < 32; sh <<= 1) rmax = fmaxf(rmax, __shfl_xor(rmax, sh));
        if (ccol == 0) atomicMax(&amax[grow], __float_as_uint(rmax));
      } else if constexpr (EPI == 3) {
        const double s = 127.0 / fmax((double)__uint_as_float(amax[grow]), 1e-5);
#pragma unroll
        for (int ni = 0; ni < 2; ++ni) {
          const int gcol = col0 + wc * 64 + ni * 32 + ccol;
          const float c = (float)acc[mi][ni][r] * f;
          const float gv = gelu_fast(c);
          Cq[(size_t)grow * ldc + gcol] =
              (int8_t)clampi((int)__builtin_rint((double)gv * s), -128, 127);
        }
      } else {
#pragma unroll
        for (int ni = 0; ni < 2; ++ni) {
          const int gcol = col0 + wc * 64 + ni * 32 + ccol;
          __builtin_nontemporal_store((float)acc[mi][ni][r] * f,
                                      &Cf[(size_t)grow * ldc + gcol]);
        }
      }
    }
  }
}

__global__ void fill_k(float* p, int n, float v) {
  int i = blockIdx.x * 256 + threadIdx.x;
  if (i < n) p[i] = v;
}

extern "C" void kernel_launch(void* const* d_in, const int* in_sizes, int n_in, void* d_out,
                              int out_size, void* d_ws, size_t ws_size, hipStream_t stream) {
  const float* x = (const float*)d_in[0];
  const float* w1 = (const float*)d_in[1];
  const float* w2 = (const float*)d_in[2];
  const float* gamma = (const float*)d_in[3];
  float* out = (float*)d_out;
  char* ws = (char*)d_ws;

  const size_t SQX = (size_t)N_TOK * D_DIM;
  const size_t SQW1 = (size_t)D_HID * D_DIM;
  const size_t SQW2 = (size_t)D_DIM * D_HID;
  const size_t SQH = (size_t)N_TOK * D_HID;
  const size_t SG16 = (size_t)N_TOK * D_HID * 2;  // 128 MiB f16 g

  size_t off = 0;
  int8_t* qx = (int8_t*)(ws + off);  off += SQX;
  int8_t* qw1 = (int8_t*)(ws + off); off += SQW1;
  int8_t* qw2 = (int8_t*)(ws + off); off += SQW2;
  int8_t* qh = (int8_t*)(ws + off);  off += SQH;
  float* sxinv = (float*)(ws + off);       off += (size_t)N_TOK * 4;
  unsigned* amaxh = (unsigned*)(ws + off); off += (size_t)N_TOK * 4;
  float* shinv = (float*)(ws + off);       off += (size_t)N_TOK * 4;
  double* wpart = (double*)(ws + off);     off += 2048 * 8;
  double* swd = (double*)(ws + off);       off += 2 * 8;
  float* wsc = (float*)(ws + off);         off += 2 * 4;
  off = (off + 255) & ~(size_t)255;
  const size_t needB = off;
  _Float16* g16 = (_Float16*)(ws + off);
  const size_t needA16 = off + SG16;

  if (ws_size < needB) {
    const float v = 100000.0f + (float)(ws_size >> 20);
    fill_k<<<(out_size + 255) / 256, 256, 0, stream>>>(out, out_size, v);
    return;
  }
  const bool pathA16 = (ws_size >= needA16);

  hipMemsetAsync(amaxh, 0, (size_t)N_TOK * 4, stream);
  wsum_k<<<2048, 256, 0, stream>>>(w1, w2, wpart);
  wfinal_k<<<1, 256, 0, stream>>>(wpart, swd, wsc);
  wquant_k<<<16384, 256, 0, stream>>>(w1, qw1, swd, 0);
  wquant_k<<<16384, 256, 0, stream>>>(w2, qw2, swd, 1);
  rmsq_k<<<N_TOK, 256, 0, stream>>>(x, gamma, qx, sxinv);

  const int nwg1 = (N_TOK / 128) * (D_HID / 128);  // 4096
  const int nwg2 = (N_TOK / 128) * (D_DIM / 128);  // 1024
  if (pathA16) {
    gemm4_i8_k<4><<<nwg1, 256, 0, stream>>>(qx, qw1, D_DIM, D_HID / 128, nullptr, g16,
                                            nullptr, D_HID, sxinv, wsc + 0, amaxh);
    hquant16_k<<<N_TOK, 256, 0, stream>>>(g16, qh, amaxh, shinv);
  } else {
    gemm4_i8_k<0><<<nwg1, 256, 0, stream>>>(qx, qw1, D_DIM, D_HID / 128, nullptr, nullptr,
                                            nullptr, D_HID, sxinv, wsc + 0, amaxh);
    scalefix_k<<<(N_TOK + 255) / 256, 256, 0, stream>>>(amaxh, shinv);
    gemm4_i8_k<3><<<nwg1, 256, 0, stream>>>(qx, qw1, D_DIM, D_HID / 128, nullptr, nullptr,
                                            qh, D_HID, sxinv, wsc + 0, amaxh);
  }
  gemm4_i8_k<2><<<nwg2, 256, 0, stream>>>(qh, qw2, D_HID, D_DIM / 128, out, nullptr,
                                          nullptr, D_DIM, shinv, wsc + 1, nullptr);
}

// Round 18
// 470.197 us; speedup vs baseline: 1.2854x; 1.2474x over previous
//
#include <hip/hip_runtime.h>
#include <cstdint>
#include <cstddef>

#define D_DIM 2048
#define D_HID 8192
#define N_TOK 8192

typedef int v4i __attribute__((ext_vector_type(4)));
typedef float v4f __attribute__((ext_vector_type(4)));
typedef _Float16 v8h __attribute__((ext_vector_type(8)));

__device__ __forceinline__ void gload16(const void* g, void* l) {
  __builtin_amdgcn_global_load_lds(
      (__attribute__((address_space(1))) void*)(void*)(const_cast<void*>(g)),
      (__attribute__((address_space(3))) void*)(void*)(l), 16, 0, 0);
}

__device__ __forceinline__ unsigned pack4i8(int a, int b, int c, int d) {
  return (unsigned)(a & 255) | ((unsigned)(b & 255) << 8) |
         ((unsigned)(c & 255) << 16) | ((unsigned)(d & 255) << 24);
}

__device__ __forceinline__ int clampi(int v, int lo, int hi) {
  return v < lo ? lo : (v > hi ? hi : v);
}

// Branch-free exact-GELU via Abramowitz-Stegun 7.1.26 erf (|eps| <= 1.5e-7 abs).
__device__ __forceinline__ float gelu_fast(float c) {
  const float ax = fabsf(c) * 0.70710678118654752440f;
  const float t = 1.0f / fmaf(0.3275911f, ax, 1.0f);
  const float poly =
      t * fmaf(t, fmaf(t, fmaf(t, fmaf(t, 1.061405429f, -1.453152027f),
                               1.421413741f), -0.284496736f), 0.254829592f);
  const float e = 1.0f - poly * __expf(-ax * ax);
  const float es = copysignf(e, c);
  return 0.5f * c * (1.0f + es);
}

// ---------------- weight |w| sum (fixed-order f64, deterministic) ------------
__global__ __launch_bounds__(256) void wsum_k(const float* __restrict__ w1,
                                              const float* __restrict__ w2,
                                              double* __restrict__ part) {
  const int b = blockIdx.x;
  const float* w = (b < 1024) ? w1 : w2;
  const size_t base = (size_t)(b & 1023) * 16384;
  const int t = threadIdx.x;
  double s = 0.0;
  for (int i = 0; i < 64; ++i) s += fabs((double)w[base + (size_t)i * 256 + t]);
  __shared__ double red[256];
  red[t] = s;
  __syncthreads();
  for (int st = 128; st; st >>= 1) {
    if (t < st) red[t] += red[t + st];
    __syncthreads();
  }
  if (!t) part[b] = red[0];
}

__global__ __launch_bounds__(256) void wfinal_k(const double* __restrict__ part,
                                                double* __restrict__ swd,
                                                float* __restrict__ wsc) {
  __shared__ double red[256];
  const int t = threadIdx.x;
  for (int m = 0; m < 2; ++m) {
    double s = part[m * 1024 + t] + part[m * 1024 + 256 + t] +
               part[m * 1024 + 512 + t] + part[m * 1024 + 768 + t];
    red[t] = s;
    __syncthreads();
    for (int st = 128; st; st >>= 1) {
      if (t < st) red[t] += red[t + st];
      __syncthreads();
    }
    if (!t) {
      double mean = red[0] / 16777216.0;
      double m2 = fmax(mean, 1e-5);
      swd[m] = 1.0 / m2;
      wsc[m] = (float)m2;
    }
    __syncthreads();
  }
}

// ---------------- ternary weight quant (f64 decision, half-even) -------------
__global__ __launch_bounds__(256) void wquant_k(const float* __restrict__ w,
                                                int8_t* __restrict__ q,
                                                const double* __restrict__ swd, int idx) {
  const double s = swd[idx];
  const size_t i = ((size_t)blockIdx.x * 256 + threadIdx.x) * 4;
  const float4 v = *(const float4*)&w[i];
  const int q0 = clampi((int)__builtin_rint((double)v.x * s), -1, 1);
  const int q1 = clampi((int)__builtin_rint((double)v.y * s), -1, 1);
  const int q2 = clampi((int)__builtin_rint((double)v.z * s), -1, 1);
  const int q3 = clampi((int)__builtin_rint((double)v.w * s), -1, 1);
  *(unsigned*)&q[i] = pack4i8(q0, q1, q2, q3);
}

// ---------------- fused RMSNorm + per-token absmax int8 quant ----------------
__global__ __launch_bounds__(256) void rmsq_k(const float* __restrict__ x,
                                              const float* __restrict__ gamma,
                                              int8_t* __restrict__ qx,
                                              float* __restrict__ sxinv) {
  const int row = blockIdx.x, t = threadIdx.x;
  const float* xr = x + (size_t)row * D_DIM;
  const v4f v0 = __builtin_nontemporal_load((const v4f*)&xr[t * 4]);
  const v4f v1 = __builtin_nontemporal_load((const v4f*)&xr[1024 + t * 4]);
  double xs[8] = {v0[0], v0[1], v0[2], v0[3], v1[0], v1[1], v1[2], v1[3]};
  double ssq = 0.0;
#pragma unroll
  for (int j = 0; j < 8; ++j) ssq += xs[j] * xs[j];
  __shared__ double red[256];
  red[t] = ssq;
  __syncthreads();
  for (int st = 128; st; st >>= 1) {
    if (t < st) red[t] += red[t + st];
    __syncthreads();
  }
  const double rn = 1.0 / sqrt(red[0] / (double)D_DIM + 1e-6);
  __syncthreads();
  const float4 g0 = *(const float4*)&gamma[t * 4];
  const float4 g1 = *(const float4*)&gamma[1024 + t * 4];
  const double gs[8] = {g0.x, g0.y, g0.z, g0.w, g1.x, g1.y, g1.z, g1.w};
  double xn[8], am = 0.0;
#pragma unroll
  for (int j = 0; j < 8; ++j) {
    xn[j] = xs[j] * rn * gs[j];
    am = fmax(am, fabs(xn[j]));
  }
  red[t] = am;
  __syncthreads();
  for (int st = 128; st; st >>= 1) {
    if (t < st) red[t] = fmax(red[t], red[t + st]);
    __syncthreads();
  }
  const double amax = fmax(red[0], 1e-5);
  const double s = 127.0 / amax;
  int q[8];
#pragma unroll
  for (int j = 0; j < 8; ++j) q[j] = clampi((int)__builtin_rint(xn[j] * s), -128, 127);
  unsigned* qo = (unsigned*)(qx + (size_t)row * D_DIM);
  qo[t] = pack4i8(q[0], q[1], q[2], q[3]);
  qo[256 + t] = pack4i8(q[4], q[5], q[6], q[7]);
  if (!t) sxinv[row] = (float)(amax / 127.0);
}

// ---------------- per-token quant of f16 gelu(h) (path A16) ------------------
__global__ __launch_bounds__(256) void hquant16_k(const _Float16* __restrict__ g16,
                                                  int8_t* __restrict__ qh,
                                                  const unsigned* __restrict__ amaxh,
                                                  float* __restrict__ shinv) {
  const int row = blockIdx.x, t = threadIdx.x;
  const _Float16* gr = g16 + (size_t)row * D_HID;
  const double am = fmax((double)__uint_as_float(amaxh[row]), 1e-5);
  const double s = 127.0 / am;
  if (!t) shinv[row] = (float)(am / 127.0);
  unsigned* qo = (unsigned*)(qh + (size_t)row * D_HID);
#pragma unroll
  for (int j = 0; j < 4; ++j) {
    const v8h v = __builtin_nontemporal_load((const v8h*)&gr[j * 2048 + t * 8]);
    int q[8];
#pragma unroll
    for (int e = 0; e < 8; ++e)
      q[e] = clampi((int)__builtin_rint((double)(float)v[e] * s), -128, 127);
    qo[j * 512 + t * 2 + 0] = pack4i8(q[0], q[1], q[2], q[3]);
    qo[j * 512 + t * 2 + 1] = pack4i8(q[4], q[5], q[6], q[7]);
  }
}

__global__ __launch_bounds__(256) void scalefix_k(const unsigned* __restrict__ amaxh,
                                                  float* __restrict__ shinv) {
  const int i = blockIdx.x * 256 + threadIdx.x;
  if (i < N_TOK)
    shinv[i] = (float)(fmax((double)__uint_as_float(amaxh[i]), 1e-5) / 127.0);
}

// ==== int8 NT GEMM, 128x128, BK=64, dbuf 2-phase, 4 blocks/CU, L2-local ======
// SESSION-BEST VERIFIED STRUCTURE (R13: 469.8 us total; conflicts 0, FETCH
// 92 MB, occupancy 41%): A+B staged in LDS via conflict-free [kslot-XOR]
// subblocks, coalesced global_load_lds source, super-column XCD-contiguous
// block order. Closed experiments: (256,5) spills acc (R14, 64 AGPRs ->
// 124 regs > 102 cap); 32x32x32 shape irreducibly bank-conflicted at this
// staging pattern and attacks a non-binding pipe (R16/R17); B-direct-to-VGPR
// latency-exposed (R12); 8-phase 256^2 monolith loses cross-block overlap
// (R6-R9). Do not revisit without new counter evidence.
// EPI: 0 gelu rowmax; 1 gelu + f32 nt-store + rowmax; 2 dequant nt-store;
//      3 gelu + i8 quant store; 4 gelu + f16 nt-store + rowmax (path A16).
template <int EPI>
__global__ __launch_bounds__(256, 4) void gemm4_i8_k(const int8_t* __restrict__ A,
                                                     const int8_t* __restrict__ B, int K,
                                                     int NB_X,
                                                     float* __restrict__ Cf,
                                                     _Float16* __restrict__ Ch,
                                                     int8_t* __restrict__ Cq, int ldc,
                                                     const float* __restrict__ rowf,
                                                     const float* __restrict__ wscp,
                                                     unsigned* __restrict__ amax) {
  __shared__ __align__(16) int8_t Al[2][8192];
  __shared__ __align__(16) int8_t Bl[2][8192];
  const int tid = threadIdx.x;
  const int wave = tid >> 6, lane = tid & 63;
  const int hi = lane >> 4, lo = lane & 15;
  const int wr = (wave >> 1) * 64, wc = (wave & 1) * 64;

  const int nwg = gridDim.x;  // multiple of 8; super-columns of 8 col-panels
  const int bid = blockIdx.x;
  const int lid = (bid & 7) * (nwg >> 3) + (bid >> 3);  // XCD-contiguous
  const int grp = lid >> 9;
  const int rem = lid & 511;
  const int by = rem >> 3;
  const int bx = (grp << 3) | (rem & 7);
  const int row0 = by * 128, col0 = bx * 128;

  // staging source: row (lane>>2), kchunk (lane&3)^((lane>>3)&3)
  const int srow = lane >> 2;
  const int skb = ((lane & 3) ^ ((lane >> 3) & 3)) * 16;
  const size_t aG0 = (size_t)(row0 + (2 * wave + 0) * 16 + srow) * K + skb;
  const size_t aG1 = (size_t)(row0 + (2 * wave + 1) * 16 + srow) * K + skb;
  const size_t bG0 = (size_t)(col0 + (2 * wave + 0) * 16 + srow) * K + skb;
  const size_t bG1 = (size_t)(col0 + (2 * wave + 1) * 16 + srow) * K + skb;
  const int ls0 = (2 * wave + 0) * 1024, ls1 = (2 * wave + 1) * 1024;
  const int NT = K >> 6;

  v4i acc[4][4];
#pragma unroll
  for (int m = 0; m < 4; ++m)
#pragma unroll
    for (int n = 0; n < 4; ++n) acc[m][n] = (v4i){0, 0, 0, 0};

  const int roff = lo * 64 + ((hi ^ ((lo >> 1) & 3)) * 16);
  const int asb = (wr >> 4);
  const int bsb = (wc >> 4);

#define STG(buf, T)                                                            \
  do {                                                                         \
    const size_t ko_ = (size_t)(T) * 64;                                       \
    gload16(A + aG0 + ko_, &Al[buf][ls0]);                                     \
    gload16(A + aG1 + ko_, &Al[buf][ls1]);                                     \
    gload16(B + bG0 + ko_, &Bl[buf][ls0]);                                     \
    gload16(B + bG1 + ko_, &Bl[buf][ls1]);                                     \
  } while (0)

  // prologue
  STG(0, 0);
  asm volatile("s_waitcnt vmcnt(0)" ::: "memory");
  __syncthreads();

  int buf = 0;
#pragma unroll 1
  for (int t = 0; t < NT; ++t) {
    if (t + 1 < NT) STG(buf ^ 1, t + 1);  // issue-early
    v4i af[4], bf[4];
#pragma unroll
    for (int m = 0; m < 4; ++m) af[m] = *(const v4i*)&Al[buf][(asb + m) * 1024 + roff];
#pragma unroll
    for (int n = 0; n < 4; ++n) bf[n] = *(const v4i*)&Bl[buf][(bsb + n) * 1024 + roff];
    __builtin_amdgcn_s_setprio(1);
#pragma unroll
    for (int m = 0; m < 4; ++m)
#pragma unroll
      for (int n = 0; n < 4; ++n)
        acc[m][n] = __builtin_amdgcn_mfma_i32_16x16x64_i8(af[m], bf[n], acc[m][n], 0, 0, 0);
    __builtin_amdgcn_s_setprio(0);
    asm volatile("s_waitcnt vmcnt(0)" ::: "memory");  // wait-late (absorbed)
    __syncthreads();
    buf ^= 1;
  }
#undef STG

  // ---- epilogue ----
  const float mw = wscp[0];
#pragma unroll
  for (int m = 0; m < 4; ++m) {
#pragma unroll
    for (int r = 0; r < 4; ++r) {
      const int grow = row0 + wr + m * 16 + hi * 4 + r;
      const float f = rowf[grow] * mw;
      if constexpr (EPI == 0 || EPI == 1 || EPI == 4) {
        float rmax = 0.f;
#pragma unroll
        for (int n = 0; n < 4; ++n) {
          const int gcol = col0 + wc + n * 16 + lo;
          const float c = (float)acc[m][n][r] * f;
          const float gv = gelu_fast(c);
          if constexpr (EPI == 1)
            __builtin_nontemporal_store(gv, &Cf[(size_t)grow * ldc + gcol]);
          if constexpr (EPI == 4)
            __builtin_nontemporal_store((_Float16)gv, &Ch[(size_t)grow * ldc + gcol]);
          rmax = fmaxf(rmax, fabsf(gv));
        }
#pragma unroll
        for (int sh = 1; sh < 16; sh <<= 1) rmax = fmaxf(rmax, __shfl_xor(rmax, sh));
        if (lo == 0) atomicMax(&amax[grow], __float_as_uint(rmax));
      } else if constexpr (EPI == 3) {
        const double s = 127.0 / fmax((double)__uint_as_float(amax[grow]), 1e-5);
#pragma unroll
        for (int n = 0; n < 4; ++n) {
          const int gcol = col0 + wc + n * 16 + lo;
          const float c = (float)acc[m][n][r] * f;
          const float gv = gelu_fast(c);
          Cq[(size_t)grow * ldc + gcol] =
              (int8_t)clampi((int)__builtin_rint((double)gv * s), -128, 127);
        }
      } else {
#pragma unroll
        for (int n = 0; n < 4; ++n) {
          const int gcol = col0 + wc + n * 16 + lo;
          __builtin_nontemporal_store((float)acc[m][n][r] * f,
                                      &Cf[(size_t)grow * ldc + gcol]);
        }
      }
    }
  }
}

__global__ void fill_k(float* p, int n, float v) {
  int i = blockIdx.x * 256 + threadIdx.x;
  if (i < n) p[i] = v;
}

extern "C" void kernel_launch(void* const* d_in, const int* in_sizes, int n_in, void* d_out,
                              int out_size, void* d_ws, size_t ws_size, hipStream_t stream) {
  const float* x = (const float*)d_in[0];
  const float* w1 = (const float*)d_in[1];
  const float* w2 = (const float*)d_in[2];
  const float* gamma = (const float*)d_in[3];
  float* out = (float*)d_out;
  char* ws = (char*)d_ws;

  const size_t SQX = (size_t)N_TOK * D_DIM;
  const size_t SQW1 = (size_t)D_HID * D_DIM;
  const size_t SQW2 = (size_t)D_DIM * D_HID;
  const size_t SQH = (size_t)N_TOK * D_HID;
  const size_t SG16 = (size_t)N_TOK * D_HID * 2;  // 128 MiB f16 g

  size_t off = 0;
  int8_t* qx = (int8_t*)(ws + off);  off += SQX;
  int8_t* qw1 = (int8_t*)(ws + off); off += SQW1;
  int8_t* qw2 = (int8_t*)(ws + off); off += SQW2;
  int8_t* qh = (int8_t*)(ws + off);  off += SQH;
  float* sxinv = (float*)(ws + off);       off += (size_t)N_TOK * 4;
  unsigned* amaxh = (unsigned*)(ws + off); off += (size_t)N_TOK * 4;
  float* shinv = (float*)(ws + off);       off += (size_t)N_TOK * 4;
  double* wpart = (double*)(ws + off);     off += 2048 * 8;
  double* swd = (double*)(ws + off);       off += 2 * 8;
  float* wsc = (float*)(ws + off);         off += 2 * 4;
  off = (off + 255) & ~(size_t)255;
  const size_t needB = off;
  _Float16* g16 = (_Float16*)(ws + off);
  const size_t needA16 = off + SG16;

  if (ws_size < needB) {
    const float v = 100000.0f + (float)(ws_size >> 20);
    fill_k<<<(out_size + 255) / 256, 256, 0, stream>>>(out, out_size, v);
    return;
  }
  const bool pathA16 = (ws_size >= needA16);

  hipMemsetAsync(amaxh, 0, (size_t)N_TOK * 4, stream);
  wsum_k<<<2048, 256, 0, stream>>>(w1, w2, wpart);
  wfinal_k<<<1, 256, 0, stream>>>(wpart, swd, wsc);
  wquant_k<<<16384, 256, 0, stream>>>(w1, qw1, swd, 0);
  wquant_k<<<16384, 256, 0, stream>>>(w2, qw2, swd, 1);
  rmsq_k<<<N_TOK, 256, 0, stream>>>(x, gamma, qx, sxinv);

  const int nwg1 = (N_TOK / 128) * (D_HID / 128);  // 4096
  const int nwg2 = (N_TOK / 128) * (D_DIM / 128);  // 1024
  if (pathA16) {
    gemm4_i8_k<4><<<nwg1, 256, 0, stream>>>(qx, qw1, D_DIM, D_HID / 128, nullptr, g16,
                                            nullptr, D_HID, sxinv, wsc + 0, amaxh);
    hquant16_k<<<N_TOK, 256, 0, stream>>>(g16, qh, amaxh, shinv);
  } else {
    gemm4_i8_k<0><<<nwg1, 256, 0, stream>>>(qx, qw1, D_DIM, D_HID / 128, nullptr, nullptr,
                                            nullptr, D_HID, sxinv, wsc + 0, amaxh);
    scalefix_k<<<(N_TOK + 255) / 256, 256, 0, stream>>>(amaxh, shinv);
    gemm4_i8_k<3><<<nwg1, 256, 0, stream>>>(qx, qw1, D_DIM, D_HID / 128, nullptr, nullptr,
                                            qh, D_HID, sxinv, wsc + 0, amaxh);
  }
  gemm4_i8_k<2><<<nwg2, 256, 0, stream>>>(qh, qw2, D_HID, D_DIM / 128, out, nullptr,
                                          nullptr, D_DIM, shinv, wsc + 1, nullptr);
}

// Round 19
// 447.469 us; speedup vs baseline: 1.3507x; 1.0508x over previous
//
#include <hip/hip_runtime.h>
#include <cstdint>
#include <cstddef>

#define D_DIM 2048
#define D_HID 8192
#define N_TOK 8192

typedef int v4i __attribute__((ext_vector_type(4)));
typedef float v4f __attribute__((ext_vector_type(4)));
typedef _Float16 v8h __attribute__((ext_vector_type(8)));

__device__ __forceinline__ void gload16(const void* g, void* l) {
  __builtin_amdgcn_global_load_lds(
      (__attribute__((address_space(1))) void*)(void*)(const_cast<void*>(g)),
      (__attribute__((address_space(3))) void*)(void*)(l), 16, 0, 0);
}

__device__ __forceinline__ unsigned pack4i8(int a, int b, int c, int d) {
  return (unsigned)(a & 255) | ((unsigned)(b & 255) << 8) |
         ((unsigned)(c & 255) << 16) | ((unsigned)(d & 255) << 24);
}

__device__ __forceinline__ int clampi(int v, int lo, int hi) {
  return v < lo ? lo : (v > hi ? hi : v);
}

// Branch-free exact-GELU via Abramowitz-Stegun 7.1.26 erf (|eps| <= 1.5e-7 abs).
__device__ __forceinline__ float gelu_fast(float c) {
  const float ax = fabsf(c) * 0.70710678118654752440f;
  const float t = 1.0f / fmaf(0.3275911f, ax, 1.0f);
  const float poly =
      t * fmaf(t, fmaf(t, fmaf(t, fmaf(t, 1.061405429f, -1.453152027f),
                               1.421413741f), -0.284496736f), 0.254829592f);
  const float e = 1.0f - poly * __expf(-ax * ax);
  const float es = copysignf(e, c);
  return 0.5f * c * (1.0f + es);
}

// ---------------- weight |w| sum (fixed-order f64, deterministic) ------------
__global__ __launch_bounds__(256) void wsum_k(const float* __restrict__ w1,
                                              const float* __restrict__ w2,
                                              double* __restrict__ part) {
  const int b = blockIdx.x;
  const float* w = (b < 1024) ? w1 : w2;
  const size_t base = (size_t)(b & 1023) * 16384;
  const int t = threadIdx.x;
  double s = 0.0;
  for (int i = 0; i < 64; ++i) s += fabs((double)w[base + (size_t)i * 256 + t]);
  __shared__ double red[256];
  red[t] = s;
  __syncthreads();
  for (int st = 128; st; st >>= 1) {
    if (t < st) red[t] += red[t + st];
    __syncthreads();
  }
  if (!t) part[b] = red[0];
}

__global__ __launch_bounds__(256) void wfinal_k(const double* __restrict__ part,
                                                double* __restrict__ swd,
                                                float* __restrict__ wsc) {
  __shared__ double red[256];
  const int t = threadIdx.x;
  for (int m = 0; m < 2; ++m) {
    double s = part[m * 1024 + t] + part[m * 1024 + 256 + t] +
               part[m * 1024 + 512 + t] + part[m * 1024 + 768 + t];
    red[t] = s;
    __syncthreads();
    for (int st = 128; st; st >>= 1) {
      if (t < st) red[t] += red[t + st];
      __syncthreads();
    }
    if (!t) {
      double mean = red[0] / 16777216.0;
      double m2 = fmax(mean, 1e-5);
      swd[m] = 1.0 / m2;
      wsc[m] = (float)m2;
    }
    __syncthreads();
  }
}

// ---------------- ternary weight quant (f64 decision, half-even) -------------
__global__ __launch_bounds__(256) void wquant_k(const float* __restrict__ w,
                                                int8_t* __restrict__ q,
                                                const double* __restrict__ swd, int idx) {
  const double s = swd[idx];
  const size_t i = ((size_t)blockIdx.x * 256 + threadIdx.x) * 4;
  const float4 v = *(const float4*)&w[i];
  const int q0 = clampi((int)__builtin_rint((double)v.x * s), -1, 1);
  const int q1 = clampi((int)__builtin_rint((double)v.y * s), -1, 1);
  const int q2 = clampi((int)__builtin_rint((double)v.z * s), -1, 1);
  const int q3 = clampi((int)__builtin_rint((double)v.w * s), -1, 1);
  *(unsigned*)&q[i] = pack4i8(q0, q1, q2, q3);
}

// ---------------- fused RMSNorm + per-token absmax int8 quant ----------------
__global__ __launch_bounds__(256) void rmsq_k(const float* __restrict__ x,
                                              const float* __restrict__ gamma,
                                              int8_t* __restrict__ qx,
                                              float* __restrict__ sxinv) {
  const int row = blockIdx.x, t = threadIdx.x;
  const float* xr = x + (size_t)row * D_DIM;
  const v4f v0 = __builtin_nontemporal_load((const v4f*)&xr[t * 4]);
  const v4f v1 = __builtin_nontemporal_load((const v4f*)&xr[1024 + t * 4]);
  double xs[8] = {v0[0], v0[1], v0[2], v0[3], v1[0], v1[1], v1[2], v1[3]};
  double ssq = 0.0;
#pragma unroll
  for (int j = 0; j < 8; ++j) ssq += xs[j] * xs[j];
  __shared__ double red[256];
  red[t] = ssq;
  __syncthreads();
  for (int st = 128; st; st >>= 1) {
    if (t < st) red[t] += red[t + st];
    __syncthreads();
  }
  const double rn = 1.0 / sqrt(red[0] / (double)D_DIM + 1e-6);
  __syncthreads();
  const float4 g0 = *(const float4*)&gamma[t * 4];
  const float4 g1 = *(const float4*)&gamma[1024 + t * 4];
  const double gs[8] = {g0.x, g0.y, g0.z, g0.w, g1.x, g1.y, g1.z, g1.w};
  double xn[8], am = 0.0;
#pragma unroll
  for (int j = 0; j < 8; ++j) {
    xn[j] = xs[j] * rn * gs[j];
    am = fmax(am, fabs(xn[j]));
  }
  red[t] = am;
  __syncthreads();
  for (int st = 128; st; st >>= 1) {
    if (t < st) red[t] = fmax(red[t], red[t + st]);
    __syncthreads();
  }
  const double amax = fmax(red[0], 1e-5);
  const double s = 127.0 / amax;
  int q[8];
#pragma unroll
  for (int j = 0; j < 8; ++j) q[j] = clampi((int)__builtin_rint(xn[j] * s), -128, 127);
  unsigned* qo = (unsigned*)(qx + (size_t)row * D_DIM);
  qo[t] = pack4i8(q[0], q[1], q[2], q[3]);
  qo[256 + t] = pack4i8(q[4], q[5], q[6], q[7]);
  if (!t) sxinv[row] = (float)(amax / 127.0);
}

// ------- fused gelu + per-token absmax + int8 quant of f16 h (path A16) ------
// Reads raw f16 h (one full row per block, 32 el/thread in regs), computes
// gelu in f32, block-reduces row absmax (fixed order, no atomics), quantizes.
// Moves GEMM1's 67M gelu evals + reduces + atomics into this memory-bound
// kernel whose VALU is otherwise idle (mem 21 us vs VALU ~15 us, overlapped).
__global__ __launch_bounds__(256) void hgeluq_k(const _Float16* __restrict__ h16,
                                                int8_t* __restrict__ qh,
                                                float* __restrict__ shinv) {
  const int row = blockIdx.x, t = threadIdx.x;
  const _Float16* hr = h16 + (size_t)row * D_HID;
  float gv[32];
  float am = 0.f;
#pragma unroll
  for (int j = 0; j < 4; ++j) {
    const v8h v = __builtin_nontemporal_load((const v8h*)&hr[j * 2048 + t * 8]);
#pragma unroll
    for (int e = 0; e < 8; ++e) {
      const float g = gelu_fast((float)v[e]);
      gv[j * 8 + e] = g;
      am = fmaxf(am, fabsf(g));
    }
  }
  __shared__ float red[256];
  red[t] = am;
  __syncthreads();
  for (int st = 128; st; st >>= 1) {
    if (t < st) red[t] = fmaxf(red[t], red[t + st]);
    __syncthreads();
  }
  const double amax = fmax((double)red[0], 1e-5);
  const double s = 127.0 / amax;
  if (!t) shinv[row] = (float)(amax / 127.0);
  unsigned* qo = (unsigned*)(qh + (size_t)row * D_HID);
#pragma unroll
  for (int j = 0; j < 4; ++j) {
    int q[8];
#pragma unroll
    for (int e = 0; e < 8; ++e)
      q[e] = clampi((int)__builtin_rint((double)gv[j * 8 + e] * s), -128, 127);
    qo[j * 512 + t * 2 + 0] = pack4i8(q[0], q[1], q[2], q[3]);
    qo[j * 512 + t * 2 + 1] = pack4i8(q[4], q[5], q[6], q[7]);
  }
}

__global__ __launch_bounds__(256) void scalefix_k(const unsigned* __restrict__ amaxh,
                                                  float* __restrict__ shinv) {
  const int i = blockIdx.x * 256 + threadIdx.x;
  if (i < N_TOK)
    shinv[i] = (float)(fmax((double)__uint_as_float(amaxh[i]), 1e-5) / 127.0);
}

// ==== int8 NT GEMM, 128x128, BK=64, dbuf 2-phase, 4 blocks/CU, L2-local ======
// SESSION-BEST VERIFIED STRUCTURE (R13/R18: conflicts 0, FETCH 92 MB,
// occupancy 41%). Closed experiments: (256,5) spills acc (R14); 32x32x32
// bank-conflicted + attacks non-binding pipe (R16/R17); B-direct latency-
// exposed (R12); monolithic 256^2 8-phase loses cross-block overlap (R6-R9).
// R19 change: EPI=5 stores RAW scaled h as f16 (no gelu/reduce/atomic in the
// epilogue) — gelu+rowmax+quant moved to hgeluq_k (GEMM2's bare-store epilogue
// runs at 94% of the per-CU LDS-port floor; GEMM1's heavy epilogue was the
// difference).
// EPI: 0 gelu rowmax (fallback); 2 dequant nt-store; 3 gelu + i8 quant store
//      (fallback); 5 raw-h f16 nt-store (path A16).
template <int EPI>
__global__ __launch_bounds__(256, 4) void gemm4_i8_k(const int8_t* __restrict__ A,
                                                     const int8_t* __restrict__ B, int K,
                                                     int NB_X,
                                                     float* __restrict__ Cf,
                                                     _Float16* __restrict__ Ch,
                                                     int8_t* __restrict__ Cq, int ldc,
                                                     const float* __restrict__ rowf,
                                                     const float* __restrict__ wscp,
                                                     unsigned* __restrict__ amax) {
  __shared__ __align__(16) int8_t Al[2][8192];
  __shared__ __align__(16) int8_t Bl[2][8192];
  const int tid = threadIdx.x;
  const int wave = tid >> 6, lane = tid & 63;
  const int hi = lane >> 4, lo = lane & 15;
  const int wr = (wave >> 1) * 64, wc = (wave & 1) * 64;

  const int nwg = gridDim.x;  // multiple of 8; super-columns of 8 col-panels
  const int bid = blockIdx.x;
  const int lid = (bid & 7) * (nwg >> 3) + (bid >> 3);  // XCD-contiguous
  const int grp = lid >> 9;
  const int rem = lid & 511;
  const int by = rem >> 3;
  const int bx = (grp << 3) | (rem & 7);
  const int row0 = by * 128, col0 = bx * 128;

  // staging source: row (lane>>2), kchunk (lane&3)^((lane>>3)&3)
  const int srow = lane >> 2;
  const int skb = ((lane & 3) ^ ((lane >> 3) & 3)) * 16;
  const size_t aG0 = (size_t)(row0 + (2 * wave + 0) * 16 + srow) * K + skb;
  const size_t aG1 = (size_t)(row0 + (2 * wave + 1) * 16 + srow) * K + skb;
  const size_t bG0 = (size_t)(col0 + (2 * wave + 0) * 16 + srow) * K + skb;
  const size_t bG1 = (size_t)(col0 + (2 * wave + 1) * 16 + srow) * K + skb;
  const int ls0 = (2 * wave + 0) * 1024, ls1 = (2 * wave + 1) * 1024;
  const int NT = K >> 6;

  v4i acc[4][4];
#pragma unroll
  for (int m = 0; m < 4; ++m)
#pragma unroll
    for (int n = 0; n < 4; ++n) acc[m][n] = (v4i){0, 0, 0, 0};

  const int roff = lo * 64 + ((hi ^ ((lo >> 1) & 3)) * 16);
  const int asb = (wr >> 4);
  const int bsb = (wc >> 4);

#define STG(buf, T)                                                            \
  do {                                                                         \
    const size_t ko_ = (size_t)(T) * 64;                                       \
    gload16(A + aG0 + ko_, &Al[buf][ls0]);                                     \
    gload16(A + aG1 + ko_, &Al[buf][ls1]);                                     \
    gload16(B + bG0 + ko_, &Bl[buf][ls0]);                                     \
    gload16(B + bG1 + ko_, &Bl[buf][ls1]);                                     \
  } while (0)

  // prologue
  STG(0, 0);
  asm volatile("s_waitcnt vmcnt(0)" ::: "memory");
  __syncthreads();

  int buf = 0;
#pragma unroll 1
  for (int t = 0; t < NT; ++t) {
    if (t + 1 < NT) STG(buf ^ 1, t + 1);  // issue-early
    v4i af[4], bf[4];
#pragma unroll
    for (int m = 0; m < 4; ++m) af[m] = *(const v4i*)&Al[buf][(asb + m) * 1024 + roff];
#pragma unroll
    for (int n = 0; n < 4; ++n) bf[n] = *(const v4i*)&Bl[buf][(bsb + n) * 1024 + roff];
    __builtin_amdgcn_s_setprio(1);
#pragma unroll
    for (int m = 0; m < 4; ++m)
#pragma unroll
      for (int n = 0; n < 4; ++n)
        acc[m][n] = __builtin_amdgcn_mfma_i32_16x16x64_i8(af[m], bf[n], acc[m][n], 0, 0, 0);
    __builtin_amdgcn_s_setprio(0);
    asm volatile("s_waitcnt vmcnt(0)" ::: "memory");  // wait-late (absorbed)
    __syncthreads();
    buf ^= 1;
  }
#undef STG

  // ---- epilogue ----
  const float mw = wscp[0];
#pragma unroll
  for (int m = 0; m < 4; ++m) {
#pragma unroll
    for (int r = 0; r < 4; ++r) {
      const int grow = row0 + wr + m * 16 + hi * 4 + r;
      const float f = rowf[grow] * mw;
      if constexpr (EPI == 5) {
#pragma unroll
        for (int n = 0; n < 4; ++n) {
          const int gcol = col0 + wc + n * 16 + lo;
          __builtin_nontemporal_store((_Float16)((float)acc[m][n][r] * f),
                                      &Ch[(size_t)grow * ldc + gcol]);
        }
      } else if constexpr (EPI == 0) {
        float rmax = 0.f;
#pragma unroll
        for (int n = 0; n < 4; ++n) {
          const int gcol = col0 + wc + n * 16 + lo;
          const float c = (float)acc[m][n][r] * f;
          const float gv = gelu_fast(c);
          rmax = fmaxf(rmax, fabsf(gv));
        }
#pragma unroll
        for (int sh = 1; sh < 16; sh <<= 1) rmax = fmaxf(rmax, __shfl_xor(rmax, sh));
        if (lo == 0) atomicMax(&amax[grow], __float_as_uint(rmax));
      } else if constexpr (EPI == 3) {
        const double s = 127.0 / fmax((double)__uint_as_float(amax[grow]), 1e-5);
#pragma unroll
        for (int n = 0; n < 4; ++n) {
          const int gcol = col0 + wc + n * 16 + lo;
          const float c = (float)acc[m][n][r] * f;
          const float gv = gelu_fast(c);
          Cq[(size_t)grow * ldc + gcol] =
              (int8_t)clampi((int)__builtin_rint((double)gv * s), -128, 127);
        }
      } else {
#pragma unroll
        for (int n = 0; n < 4; ++n) {
          const int gcol = col0 + wc + n * 16 + lo;
          __builtin_nontemporal_store((float)acc[m][n][r] * f,
                                      &Cf[(size_t)grow * ldc + gcol]);
        }
      }
    }
  }
}

__global__ void fill_k(float* p, int n, float v) {
  int i = blockIdx.x * 256 + threadIdx.x;
  if (i < n) p[i] = v;
}

extern "C" void kernel_launch(void* const* d_in, const int* in_sizes, int n_in, void* d_out,
                              int out_size, void* d_ws, size_t ws_size, hipStream_t stream) {
  const float* x = (const float*)d_in[0];
  const float* w1 = (const float*)d_in[1];
  const float* w2 = (const float*)d_in[2];
  const float* gamma = (const float*)d_in[3];
  float* out = (float*)d_out;
  char* ws = (char*)d_ws;

  const size_t SQX = (size_t)N_TOK * D_DIM;
  const size_t SQW1 = (size_t)D_HID * D_DIM;
  const size_t SQW2 = (size_t)D_DIM * D_HID;
  const size_t SQH = (size_t)N_TOK * D_HID;
  const size_t SG16 = (size_t)N_TOK * D_HID * 2;  // 128 MiB f16 h

  size_t off = 0;
  int8_t* qx = (int8_t*)(ws + off);  off += SQX;
  int8_t* qw1 = (int8_t*)(ws + off); off += SQW1;
  int8_t* qw2 = (int8_t*)(ws + off); off += SQW2;
  int8_t* qh = (int8_t*)(ws + off);  off += SQH;
  float* sxinv = (float*)(ws + off);       off += (size_t)N_TOK * 4;
  unsigned* amaxh = (unsigned*)(ws + off); off += (size_t)N_TOK * 4;
  float* shinv = (float*)(ws + off);       off += (size_t)N_TOK * 4;
  double* wpart = (double*)(ws + off);     off += 2048 * 8;
  double* swd = (double*)(ws + off);       off += 2 * 8;
  float* wsc = (float*)(ws + off);         off += 2 * 4;
  off = (off + 255) & ~(size_t)255;
  const size_t needB = off;
  _Float16* h16 = (_Float16*)(ws + off);
  const size_t needA16 = off + SG16;

  if (ws_size < needB) {
    const float v = 100000.0f + (float)(ws_size >> 20);
    fill_k<<<(out_size + 255) / 256, 256, 0, stream>>>(out, out_size, v);
    return;
  }
  const bool pathA16 = (ws_size >= needA16);

  wsum_k<<<2048, 256, 0, stream>>>(w1, w2, wpart);
  wfinal_k<<<1, 256, 0, stream>>>(wpart, swd, wsc);
  wquant_k<<<16384, 256, 0, stream>>>(w1, qw1, swd, 0);
  wquant_k<<<16384, 256, 0, stream>>>(w2, qw2, swd, 1);
  rmsq_k<<<N_TOK, 256, 0, stream>>>(x, gamma, qx, sxinv);

  const int nwg1 = (N_TOK / 128) * (D_HID / 128);  // 4096
  const int nwg2 = (N_TOK / 128) * (D_DIM / 128);  // 1024
  if (pathA16) {
    gemm4_i8_k<5><<<nwg1, 256, 0, stream>>>(qx, qw1, D_DIM, D_HID / 128, nullptr, h16,
                                            nullptr, D_HID, sxinv, wsc + 0, nullptr);
    hgeluq_k<<<N_TOK, 256, 0, stream>>>(h16, qh, shinv);
  } else {
    hipMemsetAsync(amaxh, 0, (size_t)N_TOK * 4, stream);
    gemm4_i8_k<0><<<nwg1, 256, 0, stream>>>(qx, qw1, D_DIM, D_HID / 128, nullptr, nullptr,
                                            nullptr, D_HID, sxinv, wsc + 0, amaxh);
    scalefix_k<<<(N_TOK + 255) / 256, 256, 0, stream>>>(amaxh, shinv);
    gemm4_i8_k<3><<<nwg1, 256, 0, stream>>>(qx, qw1, D_DIM, D_HID / 128, nullptr, nullptr,
                                            qh, D_HID, sxinv, wsc + 0, amaxh);
  }
  gemm4_i8_k<2><<<nwg2, 256, 0, stream>>>(qh, qw2, D_HID, D_DIM / 128, out, nullptr,
                                          nullptr, D_DIM, shinv, wsc + 1, nullptr);
}